// Round 1
// baseline (7369.041 us; speedup 1.0000x reference)
//
#include <hip/hip_runtime.h>
#include <cstdint>
#include <cstddef>

#define T_ 256
#define B_ 128
#define E_ 512
#define H_ 1024
#define BH (B_*H_)

typedef _Float16 v8h __attribute__((ext_vector_type(8)));
typedef float    v4f __attribute__((ext_vector_type(4)));

__device__ __forceinline__ float sigmoidf_(float x) {
    return 1.0f / (1.0f + __expf(-x));
}
__device__ __forceinline__ float tanhf_(float x) {
    // tanh(x) = 1 - 2/(exp(2x)+1); saturates correctly at +/-inf
    return 1.0f - 2.0f / (__expf(2.0f * x) + 1.0f);
}

// ---------------------------------------------------------------------------
// Fused per-timestep kernel. Launch k (k=0..T) runs:
//   phase A (blockIdx.z==0): layer0 at t=k      (skipped when k==T)
//   phase B (blockIdx.z==1): layer1 at t=k-1    (skipped when k==0)
// Phase B(k) depends only on phase A(k-1) and phase B(k-1) -> cross-launch
// deps only. fp16 h-shadows and hn0 are ping-ponged on (t&1) to avoid
// intra-launch RAW races (other WGs read full rows of h for the GEMM).
// WG = 32 rows x 32 hidden units (96 gate columns), 4 waves.
// Wave w: rows rh*16.. (rh=w&1), hidden hq*16.. (hq=w>>1),
// 4 accumulators: r, z, n_i (input seg), n_h (hidden seg).
// ---------------------------------------------------------------------------
__global__ __launch_bounds__(256) void gru_step(
    const int* __restrict__ bs,
    const _Float16* __restrict__ x16,   // [T][B][E]
    const _Float16* __restrict__ Wi0,   // [3072][512]
    const _Float16* __restrict__ Wh0,   // [3072][1024]
    const _Float16* __restrict__ Wi1,   // [3072][1024]
    const _Float16* __restrict__ Wh1,   // [3072][1024]
    const float* __restrict__ bias,     // [2][4][1024] : br,bz,b_in,b_hn
    float* __restrict__ h0f, float* __restrict__ h1f,      // fp32 masters
    _Float16* __restrict__ h0h, _Float16* __restrict__ h1h, // fp16 shadow x2
    _Float16* __restrict__ hn0,                             // layer0 out x2
    int k)
{
    const int phase = blockIdx.z;
    if (phase == 0 && k >= T_) return;
    if (phase == 1 && k == 0)  return;
    const int t = phase ? (k - 1) : k;
    const int bs_t = bs[t];
    const int rtile = blockIdx.y * 32;
    const int jtile = blockIdx.x * 32;
    const int tid = threadIdx.x;

    const int pr = t & 1, pw = (t + 1) & 1;
    _Float16* hh = phase ? h1h : h0h;
    const _Float16* hh_r = hh + (size_t)pr * BH;
    _Float16*       hh_w = hh + (size_t)pw * BH;

    // Inactive tile: keep the ping-pong coherent by copying the shadow tile.
    if (rtile >= bs_t) {
        if (tid < 128) {
            int r = tid >> 2, c = tid & 3;
            size_t off = (size_t)(rtile + r) * H_ + jtile + c * 8;
            *(uint4*)(hh_w + off) = *(const uint4*)(hh_r + off);
        }
        return;
    }

    // 64-half K-chunks, row pitch 88 halves (176B): 16B-aligned b128 reads,
    // only 2-way LDS bank aliasing (free).
    __shared__ _Float16 Alds[32][88];
    __shared__ _Float16 Blds[96][88];

    const _Float16 *aseg0, *aseg1, *bseg0, *bseg1;
    int apitch0, bpitch0, nch, k0ch;
    if (phase == 0) {
        aseg0 = x16 + (size_t)t * B_ * E_;  apitch0 = E_;
        aseg1 = hh_r;
        bseg0 = Wi0;  bpitch0 = E_;
        bseg1 = Wh0;
        nch = 24; k0ch = 8;        // 512/64 + 1024/64
    } else {
        aseg0 = hn0 + (size_t)pr * BH;  apitch0 = H_;
        aseg1 = hh_r;
        bseg0 = Wi1;  bpitch0 = H_;
        bseg1 = Wh1;
        nch = 32; k0ch = 16;       // 1024/64 + 1024/64
    }

    const v4f vzero = {0.f, 0.f, 0.f, 0.f};
    v4f acc[4];
    acc[0] = vzero; acc[1] = vzero; acc[2] = vzero; acc[3] = vzero;

    const int lane = tid & 63, w = tid >> 6;
    const int rh = w & 1, hq = w >> 1;
    const int m = lane & 15, q = lane >> 4;

    for (int kc = 0; kc < nch; ++kc) {
        const int seg = (kc >= k0ch);
        const int koff = seg ? (kc - k0ch) * 64 : kc * 64;
        const _Float16* as   = seg ? aseg1 : aseg0;
        const int       ap   = seg ? H_ : apitch0;
        const _Float16* bsrc = seg ? bseg1 : bseg0;
        const int       bp   = seg ? H_ : bpitch0;

        __syncthreads();
        {   // A tile: 32 rows x 64 halves, one 16B chunk per thread
            int row = tid >> 3, c = tid & 7;
            *(uint4*)&Alds[row][c * 8] =
                *(const uint4*)(as + (size_t)(rtile + row) * ap + koff + c * 8);
        }
#pragma unroll
        for (int i = 0; i < 3; ++i) {  // B tile: 96 gate cols x 64 halves
            int id = tid + i * 256;
            int cl = id >> 3, c = id & 7;
            int g = cl >> 5, j = cl & 31;
            *(uint4*)&Blds[cl][c * 8] =
                *(const uint4*)(bsrc + (size_t)(g * H_ + jtile + j) * bp + koff + c * 8);
        }
        __syncthreads();

#pragma unroll
        for (int s = 0; s < 2; ++s) {
            v8h a  = *(const v8h*)&Alds[rh * 16 + m][s * 32 + q * 8];
            v8h b0 = *(const v8h*)&Blds[ 0 + hq * 16 + m][s * 32 + q * 8];
            v8h b1 = *(const v8h*)&Blds[32 + hq * 16 + m][s * 32 + q * 8];
            v8h b2 = *(const v8h*)&Blds[64 + hq * 16 + m][s * 32 + q * 8];
            acc[0] = __builtin_amdgcn_mfma_f32_16x16x32_f16(a, b0, acc[0], 0, 0, 0);
            acc[1] = __builtin_amdgcn_mfma_f32_16x16x32_f16(a, b1, acc[1], 0, 0, 0);
            if (seg) acc[3] = __builtin_amdgcn_mfma_f32_16x16x32_f16(a, b2, acc[3], 0, 0, 0);
            else     acc[2] = __builtin_amdgcn_mfma_f32_16x16x32_f16(a, b2, acc[2], 0, 0, 0);
        }
    }

    // Epilogue. C/D layout: col = lane&15, row = quad*4 + reg.
    const float* bb = bias + phase * 4 * H_;
    float* hf = phase ? h1f : h0f;
    _Float16* hn0w = hn0 + (size_t)pr * BH;   // phase A writes hn0[t&1]
    const int colG = jtile + hq * 16 + m;
    const float br = bb[colG];
    const float bz = bb[H_ + colG];
    const float bi = bb[2 * H_ + colG];
    const float bh = bb[3 * H_ + colG];
#pragma unroll
    for (int reg = 0; reg < 4; ++reg) {
        int rowG = rtile + rh * 16 + q * 4 + reg;
        size_t off = (size_t)rowG * H_ + colG;
        float hprev = hf[off];
        float rr = sigmoidf_(acc[0][reg] + br);
        float zz = sigmoidf_(acc[1][reg] + bz);
        float nn = tanhf_(acc[2][reg] + bi + rr * (acc[3][reg] + bh));
        float hnew = (1.0f - zz) * nn + zz * hprev;
        bool act = rowG < bs_t;
        float hsel = act ? hnew : hprev;
        if (phase == 0) hn0w[off] = (_Float16)hnew;  // layer1 input: unmasked hn
        hh_w[off] = (_Float16)hsel;
        if (act) hf[off] = hnew;
    }
}

// ---------------------------------------------------------------------------
// Preamble / epilogue helpers
// ---------------------------------------------------------------------------
__global__ void cvt_f32_f16(const float* __restrict__ s, _Float16* __restrict__ d, int n) {
    int i = (blockIdx.x * 256 + threadIdx.x) * 8;
    if (i >= n) return;
    float4 v0 = *(const float4*)(s + i);
    float4 v1 = *(const float4*)(s + i + 4);
    v8h o = { (_Float16)v0.x, (_Float16)v0.y, (_Float16)v0.z, (_Float16)v0.w,
              (_Float16)v1.x, (_Float16)v1.y, (_Float16)v1.z, (_Float16)v1.w };
    *(v8h*)(d + i) = o;
}

__global__ void prep_bias(const float* __restrict__ bi0, const float* __restrict__ bh0,
                          const float* __restrict__ bi1, const float* __restrict__ bh1,
                          float* __restrict__ bias) {
    int tid = blockIdx.x * 256 + threadIdx.x;   // 2048 threads
    int l = tid >> 10, j = tid & 1023;
    const float* bi = l ? bi1 : bi0;
    const float* bh = l ? bh1 : bh0;
    float* o = bias + l * 4 * H_;
    o[j]           = bi[j] + bh[j];              // r gate combined
    o[H_ + j]      = bi[H_ + j] + bh[H_ + j];    // z gate combined
    o[2 * H_ + j]  = bi[2 * H_ + j];             // n gate, input part
    o[3 * H_ + j]  = bh[2 * H_ + j];             // n gate, hidden part
}

__global__ void gather_out(const float* __restrict__ h0f, const float* __restrict__ h1f,
                           const int* __restrict__ unsorted, float* __restrict__ out) {
    int rowid = blockIdx.x;          // 256 = L*B
    int l = rowid >> 7, b = rowid & 127;
    int src = unsorted[b];
    const float* s = (l ? h1f : h0f) + (size_t)src * H_;
    float* o = out + (size_t)rowid * H_;
    int c = threadIdx.x * 4;
    *(float4*)(o + c) = *(const float4*)(s + c);
}

// ---------------------------------------------------------------------------
extern "C" void kernel_launch(void* const* d_in, const int* in_sizes, int n_in,
                              void* d_out, int out_size, void* d_ws, size_t ws_size,
                              hipStream_t stream) {
    const float* x    = (const float*)d_in[0];
    const float* Wi0f = (const float*)d_in[1];
    const float* Wh0f = (const float*)d_in[2];
    const float* bi0  = (const float*)d_in[3];
    const float* bh0  = (const float*)d_in[4];
    const float* Wi1f = (const float*)d_in[5];
    const float* Wh1f = (const float*)d_in[6];
    const float* bi1  = (const float*)d_in[7];
    const float* bh1  = (const float*)d_in[8];
    const int*  bs       = (const int*)d_in[9];
    const int*  unsorted = (const int*)d_in[10];
    float* out = (float*)d_out;

    char* ws = (char*)d_ws;
    size_t off = 0;
    auto alloc = [&](size_t bytes) -> char* {
        char* p = ws + off;
        off += (bytes + 255) & ~(size_t)255;
        return p;
    };
    _Float16* x16 = (_Float16*)alloc((size_t)T_ * B_ * E_ * 2);
    _Float16* Wi0 = (_Float16*)alloc((size_t)3 * H_ * E_ * 2);
    _Float16* Wh0 = (_Float16*)alloc((size_t)3 * H_ * H_ * 2);
    _Float16* Wi1 = (_Float16*)alloc((size_t)3 * H_ * H_ * 2);
    _Float16* Wh1 = (_Float16*)alloc((size_t)3 * H_ * H_ * 2);
    float*    bias = (float*)alloc(2 * 4 * H_ * 4);
    char* zbase = ws + off;                  // zero-init block start
    float*    h0f = (float*)alloc((size_t)BH * 4);
    float*    h1f = (float*)alloc((size_t)BH * 4);
    _Float16* h0h = (_Float16*)alloc((size_t)2 * BH * 2);
    _Float16* h1h = (_Float16*)alloc((size_t)2 * BH * 2);
    _Float16* hn0 = (_Float16*)alloc((size_t)2 * BH * 2);
    size_t zbytes = (size_t)((ws + off) - zbase);

    // h states (fp32 masters + fp16 shadows) must start at zero; ws is poisoned.
    hipMemsetAsync(zbase, 0, zbytes, stream);

    cvt_f32_f16<<<(T_ * B_ * E_) / 2048, 256, 0, stream>>>(x, x16, T_ * B_ * E_);
    cvt_f32_f16<<<(3 * H_ * E_) / 2048, 256, 0, stream>>>(Wi0f, Wi0, 3 * H_ * E_);
    cvt_f32_f16<<<(3 * H_ * H_) / 2048, 256, 0, stream>>>(Wh0f, Wh0, 3 * H_ * H_);
    cvt_f32_f16<<<(3 * H_ * H_) / 2048, 256, 0, stream>>>(Wi1f, Wi1, 3 * H_ * H_);
    cvt_f32_f16<<<(3 * H_ * H_) / 2048, 256, 0, stream>>>(Wh1f, Wh1, 3 * H_ * H_);
    prep_bias<<<8, 256, 0, stream>>>(bi0, bh0, bi1, bh1, bias);

    dim3 grid(H_ / 32, B_ / 32, 2);   // 32 hidden-tiles x 4 row-tiles x 2 phases
    for (int k = 0; k <= T_; ++k) {
        gru_step<<<grid, 256, 0, stream>>>(bs, x16, Wi0, Wh0, Wi1, Wh1, bias,
                                           h0f, h1f, h0h, h1h, hn0, k);
    }
    gather_out<<<256, 256, 0, stream>>>(h0f, h1f, unsorted, out);
}